// Round 1
// baseline (858.247 us; speedup 1.0000x reference)
//
#include <hip/hip_runtime.h>
#include <hip/hip_bf16.h>

// Problem constants (fixed by setup_inputs)
#define B_    4
#define N_    16384
#define D_    256
#define LD_   64
#define HID_  1024
#define HW_   128          // H = W = 128
#define HSRC_ 512
#define CS_   3
#define KIN_  320          // D_ + LD_

typedef __attribute__((ext_vector_type(8))) short bf16x8;
typedef __attribute__((ext_vector_type(4))) float f32x4;

__device__ __forceinline__ float wsum(float v) {
#pragma unroll
  for (int off = 32; off; off >>= 1) v += __shfl_xor(v, off, 64);
  return v;
}

// fp32 -> bf16 round-to-nearest-even (finite inputs)
__device__ __forceinline__ unsigned short f2bf(float f) {
  unsigned int u = __float_as_uint(f);
  u = (u + 0x7fffu + ((u >> 16) & 1u)) >> 16;
  return (unsigned short)u;
}

// ---------------------------------------------------------------------------
// K0: convert fc1_w (320,1024) -> Bt1 (1024,320) bf16; fc2_w (1024,256) -> Bt2 (256,1024) bf16
__global__ __launch_bounds__(256) void k_wconv(const float* __restrict__ fc1w,
                                               const float* __restrict__ fc2w,
                                               unsigned short* __restrict__ bt1,
                                               unsigned short* __restrict__ bt2) {
  int i = blockIdx.x * 256 + threadIdx.x;
  if (i < KIN_ * HID_) {
    int n = i / KIN_, k = i % KIN_;
    bt1[i] = f2bf(fc1w[(size_t)k * HID_ + n]);
  } else {
    int j = i - KIN_ * HID_;
    if (j < D_ * HID_) {
      int n = j / HID_, k = j % HID_;
      bt2[j] = f2bf(fc2w[(size_t)k * D_ + n]);
    }
  }
}

// ---------------------------------------------------------------------------
// K1: copy x -> out0 first half (per batch)
__global__ __launch_bounds__(256) void k_copy_x(const float* __restrict__ x,
                                                float* __restrict__ out0) {
  size_t i = (size_t)blockIdx.x * 256 + threadIdx.x;  // float4 index
  size_t e = i * 4;                                    // element index
  size_t b = e / ((size_t)N_ * D_);
  size_t off = e - b * (size_t)N_ * D_;
  *(float4*)(out0 + b * (size_t)2 * N_ * D_ + off) = *(const float4*)(x + e);
}

// ---------------------------------------------------------------------------
// K2: LN(x) @ w_delta -> delta; loc_extra = clip(loc + delta*0.01, 0, 1)
//     also writes out1 = concat([loc, loc_extra], axis=1)
__global__ __launch_bounds__(256) void k_delta(const float* __restrict__ x,
                                               const float* __restrict__ loc,
                                               const float* __restrict__ wd,
                                               const float* __restrict__ bd,
                                               const float* __restrict__ g1,
                                               const float* __restrict__ b1,
                                               float* __restrict__ locex,
                                               float* __restrict__ out1) {
  int wv = threadIdx.x >> 6, lane = threadIdx.x & 63;
  int t = blockIdx.x * 4 + wv;
  const float4 xv = *(const float4*)(x + (size_t)t * D_ + lane * 4);
  float m = wsum(xv.x + xv.y + xv.z + xv.w) * (1.0f / D_);
  float d0 = xv.x - m, d1 = xv.y - m, d2 = xv.z - m, d3 = xv.w - m;
  float v = wsum(d0 * d0 + d1 * d1 + d2 * d2 + d3 * d3) * (1.0f / D_);
  float r = rsqrtf(v + 1e-5f);
  const float4 gv = *(const float4*)(g1 + lane * 4);
  const float4 bv = *(const float4*)(b1 + lane * 4);
  float n0 = d0 * r * gv.x + bv.x;
  float n1 = d1 * r * gv.y + bv.y;
  float n2 = d2 * r * gv.z + bv.z;
  float n3 = d3 * r * gv.w + bv.w;
  int i2 = lane * 8;  // (lane*4)*2
  float p0 = n0 * wd[i2 + 0] + n1 * wd[i2 + 2] + n2 * wd[i2 + 4] + n3 * wd[i2 + 6];
  float p1 = n0 * wd[i2 + 1] + n1 * wd[i2 + 3] + n2 * wd[i2 + 5] + n3 * wd[i2 + 7];
  p0 = wsum(p0);
  p1 = wsum(p1);
  if (lane == 0) {
    float lx = loc[(size_t)t * 2], ly = loc[(size_t)t * 2 + 1];
    float ex = fminf(fmaxf(lx + (p0 + bd[0]) * 0.01f, 0.0f), 1.0f);
    float ey = fminf(fmaxf(ly + (p1 + bd[1]) * 0.01f, 0.0f), 1.0f);
    locex[(size_t)t * 2] = ex;
    locex[(size_t)t * 2 + 1] = ey;
    int b = t >> 14, n = t & (N_ - 1);
    size_t o1 = (size_t)b * 2 * N_;
    out1[(o1 + n) * 2 + 0] = lx;
    out1[(o1 + n) * 2 + 1] = ly;
    out1[(o1 + N_ + n) * 2 + 0] = ex;
    out1[(o1 + N_ + n) * 2 + 1] = ey;
  }
}

// ---------------------------------------------------------------------------
// K3: token2map scatter: feat += x at rounded loc cell; cnt += 1
__global__ __launch_bounds__(256) void k_scatter(const float* __restrict__ x,
                                                 const float* __restrict__ loc,
                                                 float* __restrict__ feat,
                                                 float* __restrict__ cnt) {
  int wv = threadIdx.x >> 6, lane = threadIdx.x & 63;
  int t = blockIdx.x * 4 + wv;
  int b = t >> 14;
  float lx = fminf(fmaxf(loc[(size_t)t * 2], 0.0f), 1.0f) * 127.0f;
  float ly = fminf(fmaxf(loc[(size_t)t * 2 + 1], 0.0f), 1.0f) * 127.0f;
  int ix = (int)rintf(lx);  // round-half-even, matches jnp.round
  int iy = (int)rintf(ly);
  size_t cell = (size_t)b * (HW_ * HW_) + iy * HW_ + ix;
  const float4 xv = *(const float4*)(x + (size_t)t * D_ + lane * 4);
  float* fp = feat + cell * D_ + lane * 4;
  atomicAdd(fp + 0, xv.x);
  atomicAdd(fp + 1, xv.y);
  atomicAdd(fp + 2, xv.z);
  atomicAdd(fp + 3, xv.w);
  if (lane == 0) atomicAdd(cnt + cell, 1.0f);
}

// ---------------------------------------------------------------------------
// K4: normalize + gaussian inpaint (3x3, sigma=2) -> fmap (channel-last)
__global__ __launch_bounds__(256) void k_filter(const float* __restrict__ feat,
                                                const float* __restrict__ cnt,
                                                float* __restrict__ fmap) {
  int pix = blockIdx.x;  // b*16384 + y*128 + x
  int c = threadIdx.x;
  int b = pix >> 14;
  int p = pix & 16383;
  int y = p >> 7, xc = p & 127;
  float cc = cnt[pix];
  float outv;
  if (cc > 0.0f) {
    outv = feat[(size_t)pix * D_ + c] / (cc + 1e-6f);
  } else {
    float e1 = expf(-0.125f), e2 = expf(-0.25f);
    float sumw = 1.0f + 4.0f * e1 + 4.0f * e2;
    float gf = 0.0f, gm = 0.0f;
#pragma unroll
    for (int dy = -1; dy <= 1; ++dy)
#pragma unroll
      for (int dx = -1; dx <= 1; ++dx) {
        int ny = y + dy, nx = xc + dx;
        if (ny < 0 || ny >= HW_ || nx < 0 || nx >= HW_) continue;
        int q = (b << 14) + ny * HW_ + nx;
        float cq = cnt[q];
        if (cq > 0.0f) {
          int dd = dy * dy + dx * dx;
          float w = (dd == 0 ? 1.0f : (dd == 1 ? e1 : e2)) / sumw;
          gf += w * (feat[(size_t)q * D_ + c] / (cq + 1e-6f));
          gm += w;
        }
      }
    outv = (gm > 0.0f) ? gf / (gm + 1e-6f) : 0.0f;
  }
  fmap[(size_t)pix * D_ + c] = outv;
}

// ---------------------------------------------------------------------------
// K5: 4x4 patch bilinear sample from src + conv (64,3,4,4) + LN(64)
//     writes extra_cat[:, 256:320] as bf16. One wave per token.
__global__ __launch_bounds__(256) void k_patch(const float* __restrict__ src,
                                               const float* __restrict__ locex,
                                               const float* __restrict__ convw,
                                               const float* __restrict__ convb,
                                               const float* __restrict__ g2,
                                               const float* __restrict__ b2,
                                               unsigned short* __restrict__ ecat) {
  __shared__ float cw[LD_ * 49];
  __shared__ float patch[4][48];
  for (int i = threadIdx.x; i < LD_ * 48; i += 256)
    cw[(i / 48) * 49 + (i % 48)] = convw[i];
  int wv = threadIdx.x >> 6, lane = threadIdx.x & 63;
  int t = blockIdx.x * 4 + wv;
  int b = t >> 14;
  float ex = locex[(size_t)t * 2], ey = locex[(size_t)t * 2 + 1];
  __syncthreads();
  if (lane < 48) {
    int c = lane >> 4, p = lane & 15, py = p >> 2, px = p & 3;
    float u = ex + ((float)px - 1.5f) / 511.0f;
    float vv = ey + ((float)py - 1.5f) / 511.0f;
    float gx = u * 512.0f - 0.5f;
    float gy = vv * 512.0f - 0.5f;
    float fx = floorf(gx), fy = floorf(gy);
    float wx = gx - fx, wy = gy - fy;
    int x0 = (int)fx, y0 = (int)fy;
    const float* plane = src + (size_t)(b * CS_ + c) * (HSRC_ * HSRC_);
    float acc = 0.0f;
#pragma unroll
    for (int ty = 0; ty < 2; ++ty)
#pragma unroll
      for (int tx = 0; tx < 2; ++tx) {
        int xi = x0 + tx, yi = y0 + ty;
        float w = (tx ? wx : 1.0f - wx) * (ty ? wy : 1.0f - wy);
        if (xi >= 0 && xi < HSRC_ && yi >= 0 && yi < HSRC_)
          acc += w * plane[yi * HSRC_ + xi];
      }
    patch[wv][lane] = acc;
  }
  __syncthreads();
  float e = convb[lane];
#pragma unroll
  for (int i = 0; i < 48; ++i) e += patch[wv][i] * cw[lane * 49 + i];
  float m = wsum(e) * (1.0f / 64.0f);
  float d = e - m;
  float v = wsum(d * d) * (1.0f / 64.0f);
  float val = d * rsqrtf(v + 1e-5f) * g2[lane] + b2[lane];
  ecat[(size_t)t * KIN_ + D_ + lane] = f2bf(val);
}

// ---------------------------------------------------------------------------
// K6: bilinear sample fmap at loc_extra -> extra_cat[:, 0:256] bf16. Wave/token.
__global__ __launch_bounds__(256) void k_sample(const float* __restrict__ fmap,
                                                const float* __restrict__ locex,
                                                unsigned short* __restrict__ ecat) {
  int wv = threadIdx.x >> 6, lane = threadIdx.x & 63;
  int t = blockIdx.x * 4 + wv;
  int b = t >> 14;
  float gx = locex[(size_t)t * 2] * 128.0f - 0.5f;
  float gy = locex[(size_t)t * 2 + 1] * 128.0f - 0.5f;
  float fx = floorf(gx), fy = floorf(gy);
  float wx = gx - fx, wy = gy - fy;
  int x0 = (int)fx, y0 = (int)fy;
  const float* base = fmap + ((size_t)b << 14) * D_;
  float4 acc = {0.0f, 0.0f, 0.0f, 0.0f};
#pragma unroll
  for (int ty = 0; ty < 2; ++ty)
#pragma unroll
    for (int tx = 0; tx < 2; ++tx) {
      int xi = x0 + tx, yi = y0 + ty;
      float w = (tx ? wx : 1.0f - wx) * (ty ? wy : 1.0f - wy);
      if (xi >= 0 && xi < HW_ && yi >= 0 && yi < HW_) {
        const float4 f = *(const float4*)(base + (size_t)(yi * HW_ + xi) * D_ + lane * 4);
        acc.x += w * f.x;
        acc.y += w * f.y;
        acc.z += w * f.z;
        acc.w += w * f.w;
      }
    }
  ushort4 o;
  o.x = f2bf(acc.x);
  o.y = f2bf(acc.y);
  o.z = f2bf(acc.z);
  o.w = f2bf(acc.w);
  *(ushort4*)(ecat + (size_t)t * KIN_ + lane * 4) = o;
}

// ---------------------------------------------------------------------------
// K7/K8: bf16 MFMA GEMM. C(M,Nn) = A(M,K) @ Bt(Nn,K)^T + bias.
// GELU=1: exact gelu, store bf16 to hout (stride Nn).
// GELU=0: store fp32 to out0 at the "extra" token positions.
template <int GELU>
__global__ __launch_bounds__(256) void k_gemm(const unsigned short* __restrict__ A,
                                              const unsigned short* __restrict__ Bt,
                                              const float* __restrict__ bias, int K,
                                              int Nn, unsigned short* __restrict__ hout,
                                              float* __restrict__ out0) {
  __shared__ __align__(16) unsigned short As[64 * 40];
  __shared__ __align__(16) unsigned short Bs[64 * 40];
  int tid = threadIdx.x, wv = tid >> 6, lane = tid & 63;
  int tile_m = blockIdx.x * 64, tile_n = blockIdx.y * 64;
  int lr = tid >> 2, lc = (tid & 3) * 8;
  f32x4 acc[4];
#pragma unroll
  for (int s = 0; s < 4; ++s) acc[s] = (f32x4){0.0f, 0.0f, 0.0f, 0.0f};
  int arow = wv * 16 + (lane & 15);
  int kk = (lane >> 4) * 8;
  for (int k0 = 0; k0 < K; k0 += 32) {
    *(uint4*)(&As[lr * 40 + lc]) = *(const uint4*)(A + (size_t)(tile_m + lr) * K + k0 + lc);
    *(uint4*)(&Bs[lr * 40 + lc]) = *(const uint4*)(Bt + (size_t)(tile_n + lr) * K + k0 + lc);
    __syncthreads();
    bf16x8 af = *(const bf16x8*)(&As[arow * 40 + kk]);
#pragma unroll
    for (int s = 0; s < 4; ++s) {
      bf16x8 bfv = *(const bf16x8*)(&Bs[(s * 16 + (lane & 15)) * 40 + kk]);
      acc[s] = __builtin_amdgcn_mfma_f32_16x16x32_bf16(af, bfv, acc[s], 0, 0, 0);
    }
    __syncthreads();
  }
  int mbase = tile_m + wv * 16 + (lane >> 4) * 4;
#pragma unroll
  for (int s = 0; s < 4; ++s) {
    int n = tile_n + s * 16 + (lane & 15);
    float bv = bias[n];
#pragma unroll
    for (int r = 0; r < 4; ++r) {
      int m = mbase + r;
      float v = acc[s][r] + bv;
      if (GELU) {
        v = 0.5f * v * (1.0f + erff(v * 0.70710678118654752f));
        hout[(size_t)m * Nn + n] = f2bf(v);
      } else {
        int bb = m >> 14, ntok = m & (N_ - 1);
        out0[((size_t)bb * 2 * N_ + N_ + ntok) * D_ + n] = v;
      }
    }
  }
}

// ---------------------------------------------------------------------------
extern "C" void kernel_launch(void* const* d_in, const int* in_sizes, int n_in,
                              void* d_out, int out_size, void* d_ws, size_t ws_size,
                              hipStream_t stream) {
  const float* x = (const float*)d_in[0];
  const float* loc = (const float*)d_in[1];
  const float* src = (const float*)d_in[2];
  const float* wd = (const float*)d_in[7];
  const float* bd = (const float*)d_in[8];
  const float* g1 = (const float*)d_in[9];
  const float* b1 = (const float*)d_in[10];
  const float* cw = (const float*)d_in[11];
  const float* cb = (const float*)d_in[12];
  const float* g2 = (const float*)d_in[13];
  const float* b2 = (const float*)d_in[14];
  const float* fc1w = (const float*)d_in[15];
  const float* fc1b = (const float*)d_in[16];
  const float* fc2w = (const float*)d_in[17];
  const float* fc2b = (const float*)d_in[18];

  float* out0 = (float*)d_out;
  float* out1 = out0 + (size_t)B_ * 2 * N_ * D_;

  char* ws = (char*)d_ws;
  // Workspace layout (bytes). h (134 MB bf16) aliases feat+fmap (dead by then).
  float* feat = (float*)(ws + 0);                      //  67,108,864
  float* fmap = (float*)(ws + 67108864);               //  67,108,864
  unsigned short* h = (unsigned short*)(ws + 0);       // 134,217,728 (alias)
  float* cnt = (float*)(ws + 134217728);               //     262,144
  float* locex = (float*)(ws + 134479872);             //     524,288
  unsigned short* ecat = (unsigned short*)(ws + 135004160);  // 41,943,040
  unsigned short* bt1 = (unsigned short*)(ws + 176947200);   //    655,360
  unsigned short* bt2 = (unsigned short*)(ws + 177602560);   //    524,288

  hipMemsetAsync(feat, 0, (size_t)67108864, stream);
  hipMemsetAsync(cnt, 0, (size_t)262144, stream);

  k_wconv<<<2304, 256, 0, stream>>>(fc1w, fc2w, bt1, bt2);
  k_copy_x<<<16384, 256, 0, stream>>>(x, out0);
  k_delta<<<16384, 256, 0, stream>>>(x, loc, wd, bd, g1, b1, locex, out1);
  k_scatter<<<16384, 256, 0, stream>>>(x, loc, feat, cnt);
  k_filter<<<65536, 256, 0, stream>>>(feat, cnt, fmap);
  k_patch<<<16384, 256, 0, stream>>>(src, locex, cw, cb, g2, b2, ecat);
  k_sample<<<16384, 256, 0, stream>>>(fmap, locex, ecat);
  k_gemm<1><<<dim3(1024, 16), 256, 0, stream>>>(ecat, bt1, fc1b, KIN_, HID_, h, nullptr);
  k_gemm<0><<<dim3(1024, 4), 256, 0, stream>>>(h, bt2, fc2b, HID_, D_, nullptr, out0);
}

// Round 2
// 665.438 us; speedup vs baseline: 1.2897x; 1.2897x over previous
//
#include <hip/hip_runtime.h>
#include <hip/hip_bf16.h>

// Problem constants (fixed by setup_inputs)
#define B_    4
#define N_    16384
#define D_    256
#define LD_   64
#define HID_  1024
#define HW_   128          // H = W = 128
#define HSRC_ 512
#define CS_   3
#define KIN_  320          // D_ + LD_

typedef __attribute__((ext_vector_type(8))) short bf16x8;
typedef __attribute__((ext_vector_type(4))) float f32x4;

__device__ __forceinline__ float wsum(float v) {
#pragma unroll
  for (int off = 32; off; off >>= 1) v += __shfl_xor(v, off, 64);
  return v;
}

// fp32 -> bf16 round-to-nearest-even (finite inputs)
__device__ __forceinline__ unsigned short f2bf(float f) {
  unsigned int u = __float_as_uint(f);
  u = (u + 0x7fffu + ((u >> 16) & 1u)) >> 16;
  return (unsigned short)u;
}

// ---------------------------------------------------------------------------
// K0: convert fc1_w (320,1024) -> Bt1 (1024,320) bf16; fc2_w (1024,256) -> Bt2 (256,1024) bf16
__global__ __launch_bounds__(256) void k_wconv(const float* __restrict__ fc1w,
                                               const float* __restrict__ fc2w,
                                               unsigned short* __restrict__ bt1,
                                               unsigned short* __restrict__ bt2) {
  int i = blockIdx.x * 256 + threadIdx.x;
  if (i < KIN_ * HID_) {
    int n = i / KIN_, k = i % KIN_;
    bt1[i] = f2bf(fc1w[(size_t)k * HID_ + n]);
  } else {
    int j = i - KIN_ * HID_;
    if (j < D_ * HID_) {
      int n = j / HID_, k = j % HID_;
      bt2[j] = f2bf(fc2w[(size_t)k * D_ + n]);
    }
  }
}

// ---------------------------------------------------------------------------
// K1: copy x -> out0 first half (per batch)
__global__ __launch_bounds__(256) void k_copy_x(const float* __restrict__ x,
                                                float* __restrict__ out0) {
  size_t i = (size_t)blockIdx.x * 256 + threadIdx.x;  // float4 index
  size_t e = i * 4;                                    // element index
  size_t b = e / ((size_t)N_ * D_);
  size_t off = e - b * (size_t)N_ * D_;
  *(float4*)(out0 + b * (size_t)2 * N_ * D_ + off) = *(const float4*)(x + e);
}

// ---------------------------------------------------------------------------
// K2: LN(x) @ w_delta -> delta; loc_extra = clip(loc + delta*0.01, 0, 1)
//     also writes out1 = concat([loc, loc_extra], axis=1)
__global__ __launch_bounds__(256) void k_delta(const float* __restrict__ x,
                                               const float* __restrict__ loc,
                                               const float* __restrict__ wd,
                                               const float* __restrict__ bd,
                                               const float* __restrict__ g1,
                                               const float* __restrict__ b1,
                                               float* __restrict__ locex,
                                               float* __restrict__ out1) {
  int wv = threadIdx.x >> 6, lane = threadIdx.x & 63;
  int t = blockIdx.x * 4 + wv;
  const float4 xv = *(const float4*)(x + (size_t)t * D_ + lane * 4);
  float m = wsum(xv.x + xv.y + xv.z + xv.w) * (1.0f / D_);
  float d0 = xv.x - m, d1 = xv.y - m, d2 = xv.z - m, d3 = xv.w - m;
  float v = wsum(d0 * d0 + d1 * d1 + d2 * d2 + d3 * d3) * (1.0f / D_);
  float r = rsqrtf(v + 1e-5f);
  const float4 gv = *(const float4*)(g1 + lane * 4);
  const float4 bv = *(const float4*)(b1 + lane * 4);
  float n0 = d0 * r * gv.x + bv.x;
  float n1 = d1 * r * gv.y + bv.y;
  float n2 = d2 * r * gv.z + bv.z;
  float n3 = d3 * r * gv.w + bv.w;
  int i2 = lane * 8;  // (lane*4)*2
  float p0 = n0 * wd[i2 + 0] + n1 * wd[i2 + 2] + n2 * wd[i2 + 4] + n3 * wd[i2 + 6];
  float p1 = n0 * wd[i2 + 1] + n1 * wd[i2 + 3] + n2 * wd[i2 + 5] + n3 * wd[i2 + 7];
  p0 = wsum(p0);
  p1 = wsum(p1);
  if (lane == 0) {
    float lx = loc[(size_t)t * 2], ly = loc[(size_t)t * 2 + 1];
    float ex = fminf(fmaxf(lx + (p0 + bd[0]) * 0.01f, 0.0f), 1.0f);
    float ey = fminf(fmaxf(ly + (p1 + bd[1]) * 0.01f, 0.0f), 1.0f);
    locex[(size_t)t * 2] = ex;
    locex[(size_t)t * 2 + 1] = ey;
    int b = t >> 14, n = t & (N_ - 1);
    size_t o1 = (size_t)b * 2 * N_;
    out1[(o1 + n) * 2 + 0] = lx;
    out1[(o1 + n) * 2 + 1] = ly;
    out1[(o1 + N_ + n) * 2 + 0] = ex;
    out1[(o1 + N_ + n) * 2 + 1] = ey;
  }
}

// ---------------------------------------------------------------------------
// K3a: build per-cell linked list of tokens. head[cell] init to -1 by memset.
__global__ __launch_bounds__(256) void k_build(const float* __restrict__ loc,
                                               int* __restrict__ head,
                                               int* __restrict__ nxt) {
  int t = blockIdx.x * 256 + threadIdx.x;  // 65536 tokens
  int b = t >> 14;
  float lx = fminf(fmaxf(loc[(size_t)t * 2], 0.0f), 1.0f) * 127.0f;
  float ly = fminf(fmaxf(loc[(size_t)t * 2 + 1], 0.0f), 1.0f) * 127.0f;
  int ix = (int)rintf(lx);  // round-half-even, matches jnp.round
  int iy = (int)rintf(ly);
  int cell = (b << 14) + iy * HW_ + ix;
  nxt[t] = atomicExch(head + cell, t);
}

// ---------------------------------------------------------------------------
// K3b: one block per cell — walk token list, sum x, write NORMALIZED feat + cnt.
__global__ __launch_bounds__(256) void k_gather(const float* __restrict__ x,
                                                const int* __restrict__ head,
                                                const int* __restrict__ nxt,
                                                float* __restrict__ featn,
                                                float* __restrict__ cntf) {
  int cell = blockIdx.x;
  int tid = threadIdx.x;
  __shared__ int toks[16];
  __shared__ int scount, snext;
  float acc = 0.0f;
  int total = 0;
  int cur = head[cell];
  while (cur >= 0) {
    if (tid == 0) {
      int c = 0, p = cur;
      while (p >= 0 && c < 16) {
        toks[c++] = p;
        p = nxt[p];
      }
      scount = c;
      snext = p;
    }
    __syncthreads();
    int c = scount;
    for (int i = 0; i < c; ++i) acc += x[(size_t)toks[i] * D_ + tid];
    total += c;
    cur = snext;
    __syncthreads();
  }
  featn[(size_t)cell * D_ + tid] = (total > 0) ? acc / ((float)total + 1e-6f) : 0.0f;
  if (tid == 0) cntf[cell] = (float)total;
}

// ---------------------------------------------------------------------------
// K4: gaussian inpaint (3x3, sigma=2) over normalized feat -> fmap (channel-last)
__global__ __launch_bounds__(256) void k_filter(const float* __restrict__ featn,
                                                const float* __restrict__ cntf,
                                                float* __restrict__ fmap) {
  int pix = blockIdx.x;  // b*16384 + y*128 + x
  int c = threadIdx.x;
  int b = pix >> 14;
  int p = pix & 16383;
  int y = p >> 7, xc = p & 127;
  float cc = cntf[pix];
  float outv;
  if (cc > 0.0f) {
    outv = featn[(size_t)pix * D_ + c];
  } else {
    float e1 = expf(-0.125f), e2 = expf(-0.25f);
    float sumw = 1.0f + 4.0f * e1 + 4.0f * e2;
    float gf = 0.0f, gm = 0.0f;
#pragma unroll
    for (int dy = -1; dy <= 1; ++dy)
#pragma unroll
      for (int dx = -1; dx <= 1; ++dx) {
        int ny = y + dy, nx = xc + dx;
        if (ny < 0 || ny >= HW_ || nx < 0 || nx >= HW_) continue;
        int q = (b << 14) + ny * HW_ + nx;
        if (cntf[q] > 0.0f) {
          int dd = dy * dy + dx * dx;
          float w = (dd == 0 ? 1.0f : (dd == 1 ? e1 : e2)) / sumw;
          gf += w * featn[(size_t)q * D_ + c];
          gm += w;
        }
      }
    outv = (gm > 0.0f) ? gf / (gm + 1e-6f) : 0.0f;
  }
  fmap[(size_t)pix * D_ + c] = outv;
}

// ---------------------------------------------------------------------------
// K5: 4x4 patch bilinear sample from src + conv (64,3,4,4) + LN(64)
//     writes extra_cat[:, 256:320] as bf16. One wave per token.
__global__ __launch_bounds__(256) void k_patch(const float* __restrict__ src,
                                               const float* __restrict__ locex,
                                               const float* __restrict__ convw,
                                               const float* __restrict__ convb,
                                               const float* __restrict__ g2,
                                               const float* __restrict__ b2,
                                               unsigned short* __restrict__ ecat) {
  __shared__ float cw[LD_ * 49];
  __shared__ float patch[4][48];
  for (int i = threadIdx.x; i < LD_ * 48; i += 256)
    cw[(i / 48) * 49 + (i % 48)] = convw[i];
  int wv = threadIdx.x >> 6, lane = threadIdx.x & 63;
  int t = blockIdx.x * 4 + wv;
  int b = t >> 14;
  float ex = locex[(size_t)t * 2], ey = locex[(size_t)t * 2 + 1];
  __syncthreads();
  if (lane < 48) {
    int c = lane >> 4, p = lane & 15, py = p >> 2, px = p & 3;
    float u = ex + ((float)px - 1.5f) / 511.0f;
    float vv = ey + ((float)py - 1.5f) / 511.0f;
    float gx = u * 512.0f - 0.5f;
    float gy = vv * 512.0f - 0.5f;
    float fx = floorf(gx), fy = floorf(gy);
    float wx = gx - fx, wy = gy - fy;
    int x0 = (int)fx, y0 = (int)fy;
    const float* plane = src + (size_t)(b * CS_ + c) * (HSRC_ * HSRC_);
    float acc = 0.0f;
#pragma unroll
    for (int ty = 0; ty < 2; ++ty)
#pragma unroll
      for (int tx = 0; tx < 2; ++tx) {
        int xi = x0 + tx, yi = y0 + ty;
        float w = (tx ? wx : 1.0f - wx) * (ty ? wy : 1.0f - wy);
        if (xi >= 0 && xi < HSRC_ && yi >= 0 && yi < HSRC_)
          acc += w * plane[yi * HSRC_ + xi];
      }
    patch[wv][lane] = acc;
  }
  __syncthreads();
  float e = convb[lane];
#pragma unroll
  for (int i = 0; i < 48; ++i) e += patch[wv][i] * cw[lane * 49 + i];
  float m = wsum(e) * (1.0f / 64.0f);
  float d = e - m;
  float v = wsum(d * d) * (1.0f / 64.0f);
  float val = d * rsqrtf(v + 1e-5f) * g2[lane] + b2[lane];
  ecat[(size_t)t * KIN_ + D_ + lane] = f2bf(val);
}

// ---------------------------------------------------------------------------
// K6: bilinear sample fmap at loc_extra -> extra_cat[:, 0:256] bf16. Wave/token.
__global__ __launch_bounds__(256) void k_sample(const float* __restrict__ fmap,
                                                const float* __restrict__ locex,
                                                unsigned short* __restrict__ ecat) {
  int wv = threadIdx.x >> 6, lane = threadIdx.x & 63;
  int t = blockIdx.x * 4 + wv;
  int b = t >> 14;
  float gx = locex[(size_t)t * 2] * 128.0f - 0.5f;
  float gy = locex[(size_t)t * 2 + 1] * 128.0f - 0.5f;
  float fx = floorf(gx), fy = floorf(gy);
  float wx = gx - fx, wy = gy - fy;
  int x0 = (int)fx, y0 = (int)fy;
  const float* base = fmap + ((size_t)b << 14) * D_;
  float4 acc = {0.0f, 0.0f, 0.0f, 0.0f};
#pragma unroll
  for (int ty = 0; ty < 2; ++ty)
#pragma unroll
    for (int tx = 0; tx < 2; ++tx) {
      int xi = x0 + tx, yi = y0 + ty;
      float w = (tx ? wx : 1.0f - wx) * (ty ? wy : 1.0f - wy);
      if (xi >= 0 && xi < HW_ && yi >= 0 && yi < HW_) {
        const float4 f = *(const float4*)(base + (size_t)(yi * HW_ + xi) * D_ + lane * 4);
        acc.x += w * f.x;
        acc.y += w * f.y;
        acc.z += w * f.z;
        acc.w += w * f.w;
      }
    }
  ushort4 o;
  o.x = f2bf(acc.x);
  o.y = f2bf(acc.y);
  o.z = f2bf(acc.z);
  o.w = f2bf(acc.w);
  *(ushort4*)(ecat + (size_t)t * KIN_ + lane * 4) = o;
}

// ---------------------------------------------------------------------------
// K7/K8: bf16 MFMA GEMM. C(M,Nn) = A(M,K) @ Bt(Nn,K)^T + bias.
// GELU=1: exact gelu, store bf16 to hout (stride Nn).
// GELU=0: store fp32 to out0 at the "extra" token positions.
template <int GELU>
__global__ __launch_bounds__(256) void k_gemm(const unsigned short* __restrict__ A,
                                              const unsigned short* __restrict__ Bt,
                                              const float* __restrict__ bias, int K,
                                              int Nn, unsigned short* __restrict__ hout,
                                              float* __restrict__ out0) {
  __shared__ __align__(16) unsigned short As[64 * 40];
  __shared__ __align__(16) unsigned short Bs[64 * 40];
  int tid = threadIdx.x, wv = tid >> 6, lane = tid & 63;
  int tile_m = blockIdx.x * 64, tile_n = blockIdx.y * 64;
  int lr = tid >> 2, lc = (tid & 3) * 8;
  f32x4 acc[4];
#pragma unroll
  for (int s = 0; s < 4; ++s) acc[s] = (f32x4){0.0f, 0.0f, 0.0f, 0.0f};
  int arow = wv * 16 + (lane & 15);
  int kk = (lane >> 4) * 8;
  for (int k0 = 0; k0 < K; k0 += 32) {
    *(uint4*)(&As[lr * 40 + lc]) = *(const uint4*)(A + (size_t)(tile_m + lr) * K + k0 + lc);
    *(uint4*)(&Bs[lr * 40 + lc]) = *(const uint4*)(Bt + (size_t)(tile_n + lr) * K + k0 + lc);
    __syncthreads();
    bf16x8 af = *(const bf16x8*)(&As[arow * 40 + kk]);
#pragma unroll
    for (int s = 0; s < 4; ++s) {
      bf16x8 bfv = *(const bf16x8*)(&Bs[(s * 16 + (lane & 15)) * 40 + kk]);
      acc[s] = __builtin_amdgcn_mfma_f32_16x16x32_bf16(af, bfv, acc[s], 0, 0, 0);
    }
    __syncthreads();
  }
  int mbase = tile_m + wv * 16 + (lane >> 4) * 4;
#pragma unroll
  for (int s = 0; s < 4; ++s) {
    int n = tile_n + s * 16 + (lane & 15);
    float bv = bias[n];
#pragma unroll
    for (int r = 0; r < 4; ++r) {
      int m = mbase + r;
      float v = acc[s][r] + bv;
      if (GELU) {
        v = 0.5f * v * (1.0f + erff(v * 0.70710678118654752f));
        hout[(size_t)m * Nn + n] = f2bf(v);
      } else {
        int bb = m >> 14, ntok = m & (N_ - 1);
        out0[((size_t)bb * 2 * N_ + N_ + ntok) * D_ + n] = v;
      }
    }
  }
}

// ---------------------------------------------------------------------------
extern "C" void kernel_launch(void* const* d_in, const int* in_sizes, int n_in,
                              void* d_out, int out_size, void* d_ws, size_t ws_size,
                              hipStream_t stream) {
  const float* x = (const float*)d_in[0];
  const float* loc = (const float*)d_in[1];
  const float* src = (const float*)d_in[2];
  const float* wd = (const float*)d_in[7];
  const float* bd = (const float*)d_in[8];
  const float* g1 = (const float*)d_in[9];
  const float* b1 = (const float*)d_in[10];
  const float* cw = (const float*)d_in[11];
  const float* cb = (const float*)d_in[12];
  const float* g2 = (const float*)d_in[13];
  const float* b2 = (const float*)d_in[14];
  const float* fc1w = (const float*)d_in[15];
  const float* fc1b = (const float*)d_in[16];
  const float* fc2w = (const float*)d_in[17];
  const float* fc2b = (const float*)d_in[18];

  float* out0 = (float*)d_out;
  float* out1 = out0 + (size_t)B_ * 2 * N_ * D_;

  char* ws = (char*)d_ws;
  // Workspace layout (bytes). h (134 MB bf16) aliases featn+fmap (dead by then).
  float* featn = (float*)(ws + 0);                     //  67,108,864
  float* fmap = (float*)(ws + 67108864);               //  67,108,864
  unsigned short* h = (unsigned short*)(ws + 0);       // 134,217,728 (alias)
  float* cntf = (float*)(ws + 134217728);              //     262,144
  float* locex = (float*)(ws + 134479872);             //     524,288
  unsigned short* ecat = (unsigned short*)(ws + 135004160);  // 41,943,040
  unsigned short* bt1 = (unsigned short*)(ws + 176947200);   //    655,360
  unsigned short* bt2 = (unsigned short*)(ws + 177602560);   //    524,288
  int* head = (int*)(ws + 178126848);                  //     262,144
  int* nxt = (int*)(ws + 178388992);                   //     262,144

  hipMemsetAsync(head, 0xFF, (size_t)262144, stream);  // head[cell] = -1

  k_wconv<<<2304, 256, 0, stream>>>(fc1w, fc2w, bt1, bt2);
  k_copy_x<<<16384, 256, 0, stream>>>(x, out0);
  k_delta<<<16384, 256, 0, stream>>>(x, loc, wd, bd, g1, b1, locex, out1);
  k_build<<<256, 256, 0, stream>>>(loc, head, nxt);
  k_gather<<<65536, 256, 0, stream>>>(x, head, nxt, featn, cntf);
  k_filter<<<65536, 256, 0, stream>>>(featn, cntf, fmap);
  k_patch<<<16384, 256, 0, stream>>>(src, locex, cw, cb, g2, b2, ecat);
  k_sample<<<16384, 256, 0, stream>>>(fmap, locex, ecat);
  k_gemm<1><<<dim3(1024, 16), 256, 0, stream>>>(ecat, bt1, fc1b, KIN_, HID_, h, nullptr);
  k_gemm<0><<<dim3(1024, 4), 256, 0, stream>>>(h, bt2, fc2b, HID_, D_, nullptr, out0);
}

// Round 3
// 592.030 us; speedup vs baseline: 1.4497x; 1.1240x over previous
//
#include <hip/hip_runtime.h>
#include <hip/hip_bf16.h>

// Problem constants (fixed by setup_inputs)
#define B_    4
#define N_    16384
#define D_    256
#define LD_   64
#define HID_  1024
#define HW_   128          // H = W = 128
#define HSRC_ 512
#define CS_   3
#define KIN_  320          // D_ + LD_

typedef __attribute__((ext_vector_type(8))) short bf16x8;
typedef __attribute__((ext_vector_type(4))) float f32x4;

__device__ __forceinline__ float wsum(float v) {
#pragma unroll
  for (int off = 32; off; off >>= 1) v += __shfl_xor(v, off, 64);
  return v;
}

// fp32 -> bf16 round-to-nearest-even (finite inputs)
__device__ __forceinline__ unsigned short f2bf(float f) {
  unsigned int u = __float_as_uint(f);
  u = (u + 0x7fffu + ((u >> 16) & 1u)) >> 16;
  return (unsigned short)u;
}

// async global->LDS direct copy, 16 bytes per lane (global_load_lds_dwordx4)
__device__ __forceinline__ void async16(unsigned short* lds, const unsigned short* g) {
  __builtin_amdgcn_global_load_lds(
      (const __attribute__((address_space(1))) unsigned int*)g,
      (__attribute__((address_space(3))) unsigned int*)lds, 16, 0, 0);
}

// ---------------------------------------------------------------------------
// K0: convert fc1_w (320,1024) -> Bt1 (1024,320) bf16; fc2_w (1024,256) -> Bt2 (256,1024) bf16
__global__ __launch_bounds__(256) void k_wconv(const float* __restrict__ fc1w,
                                               const float* __restrict__ fc2w,
                                               unsigned short* __restrict__ bt1,
                                               unsigned short* __restrict__ bt2) {
  int i = blockIdx.x * 256 + threadIdx.x;
  if (i < KIN_ * HID_) {
    int n = i / KIN_, k = i % KIN_;
    bt1[i] = f2bf(fc1w[(size_t)k * HID_ + n]);
  } else {
    int j = i - KIN_ * HID_;
    if (j < D_ * HID_) {
      int n = j / HID_, k = j % HID_;
      bt2[j] = f2bf(fc2w[(size_t)k * D_ + n]);
    }
  }
}

// ---------------------------------------------------------------------------
// K1: copy x -> out0 first half (per batch)
__global__ __launch_bounds__(256) void k_copy_x(const float* __restrict__ x,
                                                float* __restrict__ out0) {
  size_t i = (size_t)blockIdx.x * 256 + threadIdx.x;  // float4 index
  size_t e = i * 4;                                    // element index
  size_t b = e / ((size_t)N_ * D_);
  size_t off = e - b * (size_t)N_ * D_;
  *(float4*)(out0 + b * (size_t)2 * N_ * D_ + off) = *(const float4*)(x + e);
}

// ---------------------------------------------------------------------------
// K2: LN(x) @ w_delta -> delta; loc_extra = clip(loc + delta*0.01, 0, 1)
//     also writes out1 = concat([loc, loc_extra], axis=1)
__global__ __launch_bounds__(256) void k_delta(const float* __restrict__ x,
                                               const float* __restrict__ loc,
                                               const float* __restrict__ wd,
                                               const float* __restrict__ bd,
                                               const float* __restrict__ g1,
                                               const float* __restrict__ b1,
                                               float* __restrict__ locex,
                                               float* __restrict__ out1) {
  int wv = threadIdx.x >> 6, lane = threadIdx.x & 63;
  int t = blockIdx.x * 4 + wv;
  const float4 xv = *(const float4*)(x + (size_t)t * D_ + lane * 4);
  float m = wsum(xv.x + xv.y + xv.z + xv.w) * (1.0f / D_);
  float d0 = xv.x - m, d1 = xv.y - m, d2 = xv.z - m, d3 = xv.w - m;
  float v = wsum(d0 * d0 + d1 * d1 + d2 * d2 + d3 * d3) * (1.0f / D_);
  float r = rsqrtf(v + 1e-5f);
  const float4 gv = *(const float4*)(g1 + lane * 4);
  const float4 bv = *(const float4*)(b1 + lane * 4);
  float n0 = d0 * r * gv.x + bv.x;
  float n1 = d1 * r * gv.y + bv.y;
  float n2 = d2 * r * gv.z + bv.z;
  float n3 = d3 * r * gv.w + bv.w;
  int i2 = lane * 8;  // (lane*4)*2
  float p0 = n0 * wd[i2 + 0] + n1 * wd[i2 + 2] + n2 * wd[i2 + 4] + n3 * wd[i2 + 6];
  float p1 = n0 * wd[i2 + 1] + n1 * wd[i2 + 3] + n2 * wd[i2 + 5] + n3 * wd[i2 + 7];
  p0 = wsum(p0);
  p1 = wsum(p1);
  if (lane == 0) {
    float lx = loc[(size_t)t * 2], ly = loc[(size_t)t * 2 + 1];
    float ex = fminf(fmaxf(lx + (p0 + bd[0]) * 0.01f, 0.0f), 1.0f);
    float ey = fminf(fmaxf(ly + (p1 + bd[1]) * 0.01f, 0.0f), 1.0f);
    locex[(size_t)t * 2] = ex;
    locex[(size_t)t * 2 + 1] = ey;
    int b = t >> 14, n = t & (N_ - 1);
    size_t o1 = (size_t)b * 2 * N_;
    out1[(o1 + n) * 2 + 0] = lx;
    out1[(o1 + n) * 2 + 1] = ly;
    out1[(o1 + N_ + n) * 2 + 0] = ex;
    out1[(o1 + N_ + n) * 2 + 1] = ey;
  }
}

// ---------------------------------------------------------------------------
// K3a: build per-cell linked list of tokens. head[cell] init to -1 by memset.
__global__ __launch_bounds__(256) void k_build(const float* __restrict__ loc,
                                               int* __restrict__ head,
                                               int* __restrict__ nxt) {
  int t = blockIdx.x * 256 + threadIdx.x;  // 65536 tokens
  int b = t >> 14;
  float lx = fminf(fmaxf(loc[(size_t)t * 2], 0.0f), 1.0f) * 127.0f;
  float ly = fminf(fmaxf(loc[(size_t)t * 2 + 1], 0.0f), 1.0f) * 127.0f;
  int ix = (int)rintf(lx);  // round-half-even, matches jnp.round
  int iy = (int)rintf(ly);
  int cell = (b << 14) + iy * HW_ + ix;
  nxt[t] = atomicExch(head + cell, t);
}

// ---------------------------------------------------------------------------
// K3b: one block per cell — walk token list, sum x, write NORMALIZED feat + cnt.
__global__ __launch_bounds__(256) void k_gather(const float* __restrict__ x,
                                                const int* __restrict__ head,
                                                const int* __restrict__ nxt,
                                                float* __restrict__ featn,
                                                float* __restrict__ cntf) {
  int cell = blockIdx.x;
  int tid = threadIdx.x;
  __shared__ int toks[16];
  __shared__ int scount, snext;
  float acc = 0.0f;
  int total = 0;
  int cur = head[cell];
  while (cur >= 0) {
    if (tid == 0) {
      int c = 0, p = cur;
      while (p >= 0 && c < 16) {
        toks[c++] = p;
        p = nxt[p];
      }
      scount = c;
      snext = p;
    }
    __syncthreads();
    int c = scount;
    for (int i = 0; i < c; ++i) acc += x[(size_t)toks[i] * D_ + tid];
    total += c;
    cur = snext;
    __syncthreads();
  }
  featn[(size_t)cell * D_ + tid] = (total > 0) ? acc / ((float)total + 1e-6f) : 0.0f;
  if (tid == 0) cntf[cell] = (float)total;
}

// ---------------------------------------------------------------------------
// K4: gaussian inpaint (3x3, sigma=2) over normalized feat -> fmap (channel-last)
__global__ __launch_bounds__(256) void k_filter(const float* __restrict__ featn,
                                                const float* __restrict__ cntf,
                                                float* __restrict__ fmap) {
  int pix = blockIdx.x;  // b*16384 + y*128 + x
  int c = threadIdx.x;
  int b = pix >> 14;
  int p = pix & 16383;
  int y = p >> 7, xc = p & 127;
  float cc = cntf[pix];
  float outv;
  if (cc > 0.0f) {
    outv = featn[(size_t)pix * D_ + c];
  } else {
    float e1 = expf(-0.125f), e2 = expf(-0.25f);
    float sumw = 1.0f + 4.0f * e1 + 4.0f * e2;
    float gf = 0.0f, gm = 0.0f;
#pragma unroll
    for (int dy = -1; dy <= 1; ++dy)
#pragma unroll
      for (int dx = -1; dx <= 1; ++dx) {
        int ny = y + dy, nx = xc + dx;
        if (ny < 0 || ny >= HW_ || nx < 0 || nx >= HW_) continue;
        int q = (b << 14) + ny * HW_ + nx;
        if (cntf[q] > 0.0f) {
          int dd = dy * dy + dx * dx;
          float w = (dd == 0 ? 1.0f : (dd == 1 ? e1 : e2)) / sumw;
          gf += w * featn[(size_t)q * D_ + c];
          gm += w;
        }
      }
    outv = (gm > 0.0f) ? gf / (gm + 1e-6f) : 0.0f;
  }
  fmap[(size_t)pix * D_ + c] = outv;
}

// ---------------------------------------------------------------------------
// K5: 4x4 patch bilinear sample from src + conv (64,3,4,4) + LN(64)
//     writes extra_cat[:, 256:320] as bf16. One wave per token.
__global__ __launch_bounds__(256) void k_patch(const float* __restrict__ src,
                                               const float* __restrict__ locex,
                                               const float* __restrict__ convw,
                                               const float* __restrict__ convb,
                                               const float* __restrict__ g2,
                                               const float* __restrict__ b2,
                                               unsigned short* __restrict__ ecat) {
  __shared__ float cw[LD_ * 49];
  __shared__ float patch[4][48];
  for (int i = threadIdx.x; i < LD_ * 48; i += 256)
    cw[(i / 48) * 49 + (i % 48)] = convw[i];
  int wv = threadIdx.x >> 6, lane = threadIdx.x & 63;
  int t = blockIdx.x * 4 + wv;
  int b = t >> 14;
  float ex = locex[(size_t)t * 2], ey = locex[(size_t)t * 2 + 1];
  __syncthreads();
  if (lane < 48) {
    int c = lane >> 4, p = lane & 15, py = p >> 2, px = p & 3;
    float u = ex + ((float)px - 1.5f) / 511.0f;
    float vv = ey + ((float)py - 1.5f) / 511.0f;
    float gx = u * 512.0f - 0.5f;
    float gy = vv * 512.0f - 0.5f;
    float fx = floorf(gx), fy = floorf(gy);
    float wx = gx - fx, wy = gy - fy;
    int x0 = (int)fx, y0 = (int)fy;
    const float* plane = src + (size_t)(b * CS_ + c) * (HSRC_ * HSRC_);
    float acc = 0.0f;
#pragma unroll
    for (int ty = 0; ty < 2; ++ty)
#pragma unroll
      for (int tx = 0; tx < 2; ++tx) {
        int xi = x0 + tx, yi = y0 + ty;
        float w = (tx ? wx : 1.0f - wx) * (ty ? wy : 1.0f - wy);
        if (xi >= 0 && xi < HSRC_ && yi >= 0 && yi < HSRC_)
          acc += w * plane[yi * HSRC_ + xi];
      }
    patch[wv][lane] = acc;
  }
  __syncthreads();
  float e = convb[lane];
#pragma unroll
  for (int i = 0; i < 48; ++i) e += patch[wv][i] * cw[lane * 49 + i];
  float m = wsum(e) * (1.0f / 64.0f);
  float d = e - m;
  float v = wsum(d * d) * (1.0f / 64.0f);
  float val = d * rsqrtf(v + 1e-5f) * g2[lane] + b2[lane];
  ecat[(size_t)t * KIN_ + D_ + lane] = f2bf(val);
}

// ---------------------------------------------------------------------------
// K6: bilinear sample fmap at loc_extra -> extra_cat[:, 0:256] bf16. Wave/token.
__global__ __launch_bounds__(256) void k_sample(const float* __restrict__ fmap,
                                                const float* __restrict__ locex,
                                                unsigned short* __restrict__ ecat) {
  int wv = threadIdx.x >> 6, lane = threadIdx.x & 63;
  int t = blockIdx.x * 4 + wv;
  int b = t >> 14;
  float gx = locex[(size_t)t * 2] * 128.0f - 0.5f;
  float gy = locex[(size_t)t * 2 + 1] * 128.0f - 0.5f;
  float fx = floorf(gx), fy = floorf(gy);
  float wx = gx - fx, wy = gy - fy;
  int x0 = (int)fx, y0 = (int)fy;
  const float* base = fmap + ((size_t)b << 14) * D_;
  float4 acc = {0.0f, 0.0f, 0.0f, 0.0f};
#pragma unroll
  for (int ty = 0; ty < 2; ++ty)
#pragma unroll
    for (int tx = 0; tx < 2; ++tx) {
      int xi = x0 + tx, yi = y0 + ty;
      float w = (tx ? wx : 1.0f - wx) * (ty ? wy : 1.0f - wy);
      if (xi >= 0 && xi < HW_ && yi >= 0 && yi < HW_) {
        const float4 f = *(const float4*)(base + (size_t)(yi * HW_ + xi) * D_ + lane * 4);
        acc.x += w * f.x;
        acc.y += w * f.y;
        acc.z += w * f.z;
        acc.w += w * f.w;
      }
    }
  ushort4 o;
  o.x = f2bf(acc.x);
  o.y = f2bf(acc.y);
  o.z = f2bf(acc.z);
  o.w = f2bf(acc.w);
  *(ushort4*)(ecat + (size_t)t * KIN_ + lane * 4) = o;
}

// ---------------------------------------------------------------------------
// K7/K8: m97-style 128x128 bf16 MFMA GEMM. C(M,Nn) = A(M,K) @ Bt(Nn,K)^T + bias.
// 4 waves, each computes a 64x64 quadrant = 4x4 MFMA 16x16x32 tiles.
// global_load_lds width-16 staging into unpadded lane-ordered LDS.
// XCD-aware swizzle: XCD (lin&7) owns m-tiles with (m%8==xcd), n innermost,
// so each A-tile is fetched into exactly one XCD L2, once.
// GELU=1: exact gelu, store bf16 to hout (stride Nn).
// GELU=0: store fp32 to out0 at the "extra" token positions.
template <int GELU>
__global__ __launch_bounds__(256) void k_gemm128(const unsigned short* __restrict__ A,
                                                 const unsigned short* __restrict__ Bt,
                                                 const float* __restrict__ bias, int K,
                                                 int Nn, unsigned short* __restrict__ hout,
                                                 float* __restrict__ out0) {
  __shared__ __align__(16) unsigned short As[128 * 32];
  __shared__ __align__(16) unsigned short Bs[128 * 32];
  int tid = threadIdx.x, wv = tid >> 6, lane = tid & 63;
  int wm = wv & 1, wn = wv >> 1;

  // XCD-aware tile assignment
  int nt_cnt = gridDim.x;  // # n-tiles (8 or 2)
  int lin = blockIdx.y * nt_cnt + blockIdx.x;
  int xcd = lin & 7;
  int slot = lin >> 3;
  int tile_n = (slot % nt_cnt) * 128;
  int tile_m = ((slot / nt_cnt) * 8 + xcd) * 128;

  f32x4 acc[4][4];
#pragma unroll
  for (int i = 0; i < 4; ++i)
#pragma unroll
    for (int j = 0; j < 4; ++j) acc[i][j] = (f32x4){0.0f, 0.0f, 0.0f, 0.0f};

  // staging: thread t covers LDS shorts [t*8, t*8+8) (row t/4, col (t%4)*8)
  int r0 = tid >> 2, c0 = (tid & 3) * 8;
  const unsigned short* ga = A + (size_t)(tile_m + r0) * K + c0;
  const unsigned short* gb = Bt + (size_t)(tile_n + r0) * K + c0;
  size_t rowskip = (size_t)64 * K;
  unsigned short* lA0 = As + tid * 8;
  unsigned short* lA1 = As + 2048 + tid * 8;
  unsigned short* lB0 = Bs + tid * 8;
  unsigned short* lB1 = Bs + 2048 + tid * 8;

  int ar = wm * 64 + (lane & 15);
  int br = wn * 64 + (lane & 15);
  int kk = (lane >> 4) * 8;

  for (int k0 = 0; k0 < K; k0 += 32) {
    async16(lA0, ga);
    async16(lA1, ga + rowskip);
    async16(lB0, gb);
    async16(lB1, gb + rowskip);
    ga += 32;
    gb += 32;
    __syncthreads();
    bf16x8 afr[4], bfr[4];
#pragma unroll
    for (int i = 0; i < 4; ++i) {
      afr[i] = *(const bf16x8*)(As + (ar + i * 16) * 32 + kk);
      bfr[i] = *(const bf16x8*)(Bs + (br + i * 16) * 32 + kk);
    }
#pragma unroll
    for (int mt = 0; mt < 4; ++mt)
#pragma unroll
      for (int nt = 0; nt < 4; ++nt)
        acc[mt][nt] =
            __builtin_amdgcn_mfma_f32_16x16x32_bf16(afr[mt], bfr[nt], acc[mt][nt], 0, 0, 0);
    __syncthreads();
  }

#pragma unroll
  for (int nt = 0; nt < 4; ++nt) {
    int n = tile_n + wn * 64 + nt * 16 + (lane & 15);
    float bv = bias[n];
#pragma unroll
    for (int mt = 0; mt < 4; ++mt) {
      int mbase = tile_m + wm * 64 + mt * 16 + (lane >> 4) * 4;
#pragma unroll
      for (int r = 0; r < 4; ++r) {
        int m = mbase + r;
        float v = acc[mt][nt][r] + bv;
        if (GELU) {
          v = 0.5f * v * (1.0f + erff(v * 0.70710678118654752f));
          hout[(size_t)m * Nn + n] = f2bf(v);
        } else {
          int bb = m >> 14, ntok = m & (N_ - 1);
          out0[((size_t)bb * 2 * N_ + N_ + ntok) * D_ + n] = v;
        }
      }
    }
  }
}

// ---------------------------------------------------------------------------
extern "C" void kernel_launch(void* const* d_in, const int* in_sizes, int n_in,
                              void* d_out, int out_size, void* d_ws, size_t ws_size,
                              hipStream_t stream) {
  const float* x = (const float*)d_in[0];
  const float* loc = (const float*)d_in[1];
  const float* src = (const float*)d_in[2];
  const float* wd = (const float*)d_in[7];
  const float* bd = (const float*)d_in[8];
  const float* g1 = (const float*)d_in[9];
  const float* b1 = (const float*)d_in[10];
  const float* cw = (const float*)d_in[11];
  const float* cb = (const float*)d_in[12];
  const float* g2 = (const float*)d_in[13];
  const float* b2 = (const float*)d_in[14];
  const float* fc1w = (const float*)d_in[15];
  const float* fc1b = (const float*)d_in[16];
  const float* fc2w = (const float*)d_in[17];
  const float* fc2b = (const float*)d_in[18];

  float* out0 = (float*)d_out;
  float* out1 = out0 + (size_t)B_ * 2 * N_ * D_;

  char* ws = (char*)d_ws;
  // Workspace layout (bytes). h (134 MB bf16) aliases featn+fmap (dead by then).
  float* featn = (float*)(ws + 0);                     //  67,108,864
  float* fmap = (float*)(ws + 67108864);               //  67,108,864
  unsigned short* h = (unsigned short*)(ws + 0);       // 134,217,728 (alias)
  float* cntf = (float*)(ws + 134217728);              //     262,144
  float* locex = (float*)(ws + 134479872);             //     524,288
  unsigned short* ecat = (unsigned short*)(ws + 135004160);  // 41,943,040
  unsigned short* bt1 = (unsigned short*)(ws + 176947200);   //    655,360
  unsigned short* bt2 = (unsigned short*)(ws + 177602560);   //    524,288
  int* head = (int*)(ws + 178126848);                  //     262,144
  int* nxt = (int*)(ws + 178388992);                   //     262,144

  hipMemsetAsync(head, 0xFF, (size_t)262144, stream);  // head[cell] = -1

  k_wconv<<<2304, 256, 0, stream>>>(fc1w, fc2w, bt1, bt2);
  k_copy_x<<<16384, 256, 0, stream>>>(x, out0);
  k_delta<<<16384, 256, 0, stream>>>(x, loc, wd, bd, g1, b1, locex, out1);
  k_build<<<256, 256, 0, stream>>>(loc, head, nxt);
  k_gather<<<65536, 256, 0, stream>>>(x, head, nxt, featn, cntf);
  k_filter<<<65536, 256, 0, stream>>>(featn, cntf, fmap);
  k_patch<<<16384, 256, 0, stream>>>(src, locex, cw, cb, g2, b2, ecat);
  k_sample<<<16384, 256, 0, stream>>>(fmap, locex, ecat);
  k_gemm128<1><<<dim3(8, 512), 256, 0, stream>>>(ecat, bt1, fc1b, KIN_, HID_, h, nullptr);
  k_gemm128<0><<<dim3(2, 512), 256, 0, stream>>>(h, bt2, fc2b, HID_, D_, nullptr, out0);
}

// Round 4
// 563.020 us; speedup vs baseline: 1.5244x; 1.0515x over previous
//
#include <hip/hip_runtime.h>
#include <hip/hip_bf16.h>

// Problem constants (fixed by setup_inputs)
#define B_    4
#define N_    16384
#define D_    256
#define LD_   64
#define HID_  1024
#define HW_   128          // H = W = 128
#define HSRC_ 512
#define CS_   3
#define KIN_  320          // D_ + LD_

typedef __attribute__((ext_vector_type(8))) short bf16x8;
typedef __attribute__((ext_vector_type(4))) float f32x4;

__device__ __forceinline__ float wsum(float v) {
#pragma unroll
  for (int off = 32; off; off >>= 1) v += __shfl_xor(v, off, 64);
  return v;
}

// fp32 -> bf16 round-to-nearest-even (finite inputs)
__device__ __forceinline__ unsigned short f2bf(float f) {
  unsigned int u = __float_as_uint(f);
  u = (u + 0x7fffu + ((u >> 16) & 1u)) >> 16;
  return (unsigned short)u;
}
__device__ __forceinline__ float b2f(unsigned short u) {
  return __uint_as_float(((unsigned int)u) << 16);
}

// fast exact-ish gelu: tanh form, max err ~3e-4 (below bf16 quantum of h)
__device__ __forceinline__ float gelu_f(float x) {
  float z = 0.7978845608028654f * (x + 0.044715f * x * x * x);
  float e = __expf(2.0f * z);
  float th = 1.0f - 2.0f / (e + 1.0f);  // tanh(z), overflow-safe
  return 0.5f * x * (1.0f + th);
}

// async global->LDS direct copy, 16 bytes per lane (global_load_lds_dwordx4)
__device__ __forceinline__ void async16(unsigned short* lds, const unsigned short* g) {
  __builtin_amdgcn_global_load_lds(
      (const __attribute__((address_space(1))) unsigned int*)g,
      (__attribute__((address_space(3))) unsigned int*)lds, 16, 0, 0);
}

// ---------------------------------------------------------------------------
// K0: convert fc1_w (320,1024) -> Bt1 (1024,320) bf16; fc2_w (1024,256) -> Bt2 (256,1024) bf16
__global__ __launch_bounds__(256) void k_wconv(const float* __restrict__ fc1w,
                                               const float* __restrict__ fc2w,
                                               unsigned short* __restrict__ bt1,
                                               unsigned short* __restrict__ bt2) {
  int i = blockIdx.x * 256 + threadIdx.x;
  if (i < KIN_ * HID_) {
    int n = i / KIN_, k = i % KIN_;
    bt1[i] = f2bf(fc1w[(size_t)k * HID_ + n]);
  } else {
    int j = i - KIN_ * HID_;
    if (j < D_ * HID_) {
      int n = j / HID_, k = j % HID_;
      bt2[j] = f2bf(fc2w[(size_t)k * D_ + n]);
    }
  }
}

// ---------------------------------------------------------------------------
// K2: fused — LN(x)@w_delta -> loc_extra; out1 = [loc, loc_extra];
//     out0 first half = x (copy); per-cell linked list build (head/nxt).
__global__ __launch_bounds__(256) void k_delta(const float* __restrict__ x,
                                               const float* __restrict__ loc,
                                               const float* __restrict__ wd,
                                               const float* __restrict__ bd,
                                               const float* __restrict__ g1,
                                               const float* __restrict__ b1,
                                               float* __restrict__ locex,
                                               float* __restrict__ out1,
                                               float* __restrict__ out0,
                                               int* __restrict__ head,
                                               int* __restrict__ nxt) {
  int wv = threadIdx.x >> 6, lane = threadIdx.x & 63;
  int t = blockIdx.x * 4 + wv;
  int b = t >> 14, n = t & (N_ - 1);
  const float4 xv = *(const float4*)(x + (size_t)t * D_ + lane * 4);
  // copy x into out0 first half
  *(float4*)(out0 + ((size_t)b * 2 * N_ + n) * D_ + lane * 4) = xv;
  float m = wsum(xv.x + xv.y + xv.z + xv.w) * (1.0f / D_);
  float d0 = xv.x - m, d1 = xv.y - m, d2 = xv.z - m, d3 = xv.w - m;
  float v = wsum(d0 * d0 + d1 * d1 + d2 * d2 + d3 * d3) * (1.0f / D_);
  float r = rsqrtf(v + 1e-5f);
  const float4 gv = *(const float4*)(g1 + lane * 4);
  const float4 bv = *(const float4*)(b1 + lane * 4);
  float n0 = d0 * r * gv.x + bv.x;
  float n1 = d1 * r * gv.y + bv.y;
  float n2 = d2 * r * gv.z + bv.z;
  float n3 = d3 * r * gv.w + bv.w;
  int i2 = lane * 8;  // (lane*4)*2
  float p0 = n0 * wd[i2 + 0] + n1 * wd[i2 + 2] + n2 * wd[i2 + 4] + n3 * wd[i2 + 6];
  float p1 = n0 * wd[i2 + 1] + n1 * wd[i2 + 3] + n2 * wd[i2 + 5] + n3 * wd[i2 + 7];
  p0 = wsum(p0);
  p1 = wsum(p1);
  if (lane == 0) {
    float lx = loc[(size_t)t * 2], ly = loc[(size_t)t * 2 + 1];
    float ex = fminf(fmaxf(lx + (p0 + bd[0]) * 0.01f, 0.0f), 1.0f);
    float ey = fminf(fmaxf(ly + (p1 + bd[1]) * 0.01f, 0.0f), 1.0f);
    locex[(size_t)t * 2] = ex;
    locex[(size_t)t * 2 + 1] = ey;
    size_t o1 = (size_t)b * 2 * N_;
    out1[(o1 + n) * 2 + 0] = lx;
    out1[(o1 + n) * 2 + 1] = ly;
    out1[(o1 + N_ + n) * 2 + 0] = ex;
    out1[(o1 + N_ + n) * 2 + 1] = ey;
    // token2map linked-list build (uses raw loc)
    float cx = fminf(fmaxf(lx, 0.0f), 1.0f) * 127.0f;
    float cy = fminf(fmaxf(ly, 0.0f), 1.0f) * 127.0f;
    int ix = (int)rintf(cx);  // round-half-even, matches jnp.round
    int iy = (int)rintf(cy);
    int cell = (b << 14) + iy * HW_ + ix;
    nxt[t] = atomicExch(head + cell, t);
  }
}

// ---------------------------------------------------------------------------
// K3b: one block per cell — walk token list, sum x, write NORMALIZED feat (bf16) + cnt.
__global__ __launch_bounds__(256) void k_gather(const float* __restrict__ x,
                                                const int* __restrict__ head,
                                                const int* __restrict__ nxt,
                                                unsigned short* __restrict__ featn,
                                                float* __restrict__ cntf) {
  int cell = blockIdx.x;
  int tid = threadIdx.x;
  __shared__ int toks[16];
  __shared__ int scount, snext;
  float acc = 0.0f;
  int total = 0;
  int cur = head[cell];
  while (cur >= 0) {
    if (tid == 0) {
      int c = 0, p = cur;
      while (p >= 0 && c < 16) {
        toks[c++] = p;
        p = nxt[p];
      }
      scount = c;
      snext = p;
    }
    __syncthreads();
    int c = scount;
    for (int i = 0; i < c; ++i) acc += x[(size_t)toks[i] * D_ + tid];
    total += c;
    cur = snext;
    __syncthreads();
  }
  featn[(size_t)cell * D_ + tid] = f2bf((total > 0) ? acc / ((float)total + 1e-6f) : 0.0f);
  if (tid == 0) cntf[cell] = (float)total;
}

// ---------------------------------------------------------------------------
// K4: gaussian inpaint (3x3, sigma=2) over normalized feat -> fmap (bf16, channel-last)
__global__ __launch_bounds__(256) void k_filter(const unsigned short* __restrict__ featn,
                                                const float* __restrict__ cntf,
                                                unsigned short* __restrict__ fmap) {
  int pix = blockIdx.x;  // b*16384 + y*128 + x
  int c = threadIdx.x;
  int b = pix >> 14;
  int p = pix & 16383;
  int y = p >> 7, xc = p & 127;
  float cc = cntf[pix];
  unsigned short outv;
  if (cc > 0.0f) {
    outv = featn[(size_t)pix * D_ + c];
  } else {
    float e1 = expf(-0.125f), e2 = expf(-0.25f);
    float sumw = 1.0f + 4.0f * e1 + 4.0f * e2;
    float gf = 0.0f, gm = 0.0f;
#pragma unroll
    for (int dy = -1; dy <= 1; ++dy)
#pragma unroll
      for (int dx = -1; dx <= 1; ++dx) {
        int ny = y + dy, nx = xc + dx;
        if (ny < 0 || ny >= HW_ || nx < 0 || nx >= HW_) continue;
        int q = (b << 14) + ny * HW_ + nx;
        if (cntf[q] > 0.0f) {
          int dd = dy * dy + dx * dx;
          float w = (dd == 0 ? 1.0f : (dd == 1 ? e1 : e2)) / sumw;
          gf += w * b2f(featn[(size_t)q * D_ + c]);
          gm += w;
        }
      }
    outv = f2bf((gm > 0.0f) ? gf / (gm + 1e-6f) : 0.0f);
  }
  fmap[(size_t)pix * D_ + c] = outv;
}

// ---------------------------------------------------------------------------
// K5: 4x4 patch bilinear sample from src + conv (64,3,4,4) + LN(64)
//     writes extra_cat[:, 256:320] as bf16. One wave per token.
__global__ __launch_bounds__(256) void k_patch(const float* __restrict__ src,
                                               const float* __restrict__ locex,
                                               const float* __restrict__ convw,
                                               const float* __restrict__ convb,
                                               const float* __restrict__ g2,
                                               const float* __restrict__ b2,
                                               unsigned short* __restrict__ ecat) {
  __shared__ float cw[LD_ * 49];
  __shared__ float patch[4][48];
  for (int i = threadIdx.x; i < LD_ * 48; i += 256)
    cw[(i / 48) * 49 + (i % 48)] = convw[i];
  int wv = threadIdx.x >> 6, lane = threadIdx.x & 63;
  int t = blockIdx.x * 4 + wv;
  int b = t >> 14;
  float ex = locex[(size_t)t * 2], ey = locex[(size_t)t * 2 + 1];
  __syncthreads();
  if (lane < 48) {
    int c = lane >> 4, p = lane & 15, py = p >> 2, px = p & 3;
    float u = ex + ((float)px - 1.5f) / 511.0f;
    float vv = ey + ((float)py - 1.5f) / 511.0f;
    float gx = u * 512.0f - 0.5f;
    float gy = vv * 512.0f - 0.5f;
    float fx = floorf(gx), fy = floorf(gy);
    float wx = gx - fx, wy = gy - fy;
    int x0 = (int)fx, y0 = (int)fy;
    const float* plane = src + (size_t)(b * CS_ + c) * (HSRC_ * HSRC_);
    float acc = 0.0f;
#pragma unroll
    for (int ty = 0; ty < 2; ++ty)
#pragma unroll
      for (int tx = 0; tx < 2; ++tx) {
        int xi = x0 + tx, yi = y0 + ty;
        float w = (tx ? wx : 1.0f - wx) * (ty ? wy : 1.0f - wy);
        if (xi >= 0 && xi < HSRC_ && yi >= 0 && yi < HSRC_)
          acc += w * plane[yi * HSRC_ + xi];
      }
    patch[wv][lane] = acc;
  }
  __syncthreads();
  float e = convb[lane];
#pragma unroll
  for (int i = 0; i < 48; ++i) e += patch[wv][i] * cw[lane * 49 + i];
  float m = wsum(e) * (1.0f / 64.0f);
  float d = e - m;
  float v = wsum(d * d) * (1.0f / 64.0f);
  float val = d * rsqrtf(v + 1e-5f) * g2[lane] + b2[lane];
  ecat[(size_t)t * KIN_ + D_ + lane] = f2bf(val);
}

// ---------------------------------------------------------------------------
// K6: bilinear sample fmap (bf16) at loc_extra -> extra_cat[:, 0:256] bf16. Wave/token.
__global__ __launch_bounds__(256) void k_sample(const unsigned short* __restrict__ fmap,
                                                const float* __restrict__ locex,
                                                unsigned short* __restrict__ ecat) {
  int wv = threadIdx.x >> 6, lane = threadIdx.x & 63;
  int t = blockIdx.x * 4 + wv;
  int b = t >> 14;
  float gx = locex[(size_t)t * 2] * 128.0f - 0.5f;
  float gy = locex[(size_t)t * 2 + 1] * 128.0f - 0.5f;
  float fx = floorf(gx), fy = floorf(gy);
  float wx = gx - fx, wy = gy - fy;
  int x0 = (int)fx, y0 = (int)fy;
  const unsigned short* base = fmap + (((size_t)b << 14)) * D_;
  float4 acc = {0.0f, 0.0f, 0.0f, 0.0f};
#pragma unroll
  for (int ty = 0; ty < 2; ++ty)
#pragma unroll
    for (int tx = 0; tx < 2; ++tx) {
      int xi = x0 + tx, yi = y0 + ty;
      float w = (tx ? wx : 1.0f - wx) * (ty ? wy : 1.0f - wy);
      if (xi >= 0 && xi < HW_ && yi >= 0 && yi < HW_) {
        ushort4 f = *(const ushort4*)(base + (size_t)(yi * HW_ + xi) * D_ + lane * 4);
        acc.x += w * b2f(f.x);
        acc.y += w * b2f(f.y);
        acc.z += w * b2f(f.z);
        acc.w += w * b2f(f.w);
      }
    }
  ushort4 o;
  o.x = f2bf(acc.x);
  o.y = f2bf(acc.y);
  o.z = f2bf(acc.z);
  o.w = f2bf(acc.w);
  *(ushort4*)(ecat + (size_t)t * KIN_ + lane * 4) = o;
}

// ---------------------------------------------------------------------------
// K7/K8: 128x128 bf16 MFMA GEMM, BK=64, xor-swizzled LDS, LDS-staged epilogue.
// C(M,Nn) = A(M,K) @ Bt(Nn,K)^T + bias.
// GELU=1: fast gelu, bf16 out via LDS re-tile (coalesced 256B row stores).
// GELU=0: fp32 direct store to out0 at the "extra" token positions (64B-aligned).
template <int GELU>
__global__ __launch_bounds__(256) void k_gemm128(const unsigned short* __restrict__ A,
                                                 const unsigned short* __restrict__ Bt,
                                                 const float* __restrict__ bias, int K,
                                                 int Nn, unsigned short* __restrict__ hout,
                                                 float* __restrict__ out0) {
  __shared__ __align__(16) unsigned short sh[16384];  // As[0:8192], Bs[8192:16384]
  unsigned short* As = sh;
  unsigned short* Bs = sh + 8192;
  int tid = threadIdx.x, wv = tid >> 6, lane = tid & 63;
  int wm = wv & 1, wn = wv >> 1;

  // XCD-aware tile assignment: xcd owns m%8==xcd tiles, n innermost
  int nt_cnt = gridDim.x;
  int lin = blockIdx.y * nt_cnt + blockIdx.x;
  int xcd = lin & 7;
  int slot = lin >> 3;
  int tile_n = (slot % nt_cnt) * 128;
  int tile_m = ((slot / nt_cnt) * 8 + xcd) * 128;

  f32x4 acc[4][4];
#pragma unroll
  for (int i = 0; i < 4; ++i)
#pragma unroll
    for (int j = 0; j < 4; ++j) acc[i][j] = (f32x4){0.0f, 0.0f, 0.0f, 0.0f};

  // staging: thread t -> row t>>3 (of 32-row chunk), 16B chunk (t&7)^(row&7) [xor swizzle]
  int srow = tid >> 3;
  int schunk = (tid & 7) ^ (srow & 7);
  const unsigned short* ga = A + (size_t)(tile_m + srow) * K + schunk * 8;
  const unsigned short* gb = Bt + (size_t)(tile_n + srow) * K + schunk * 8;
  size_t skip = (size_t)32 * K;
  int lofs = tid * 8;  // shorts; lane-ordered (wave base + lane*16B)

  int ar = wm * 64 + (lane & 15);
  int br = wn * 64 + (lane & 15);
  int ksel = lane >> 4;  // which 16B chunk within 32-col k-step
  int sw = lane & 7;     // xor key (rows: (ar+i*16)&7 == lane&7)

  for (int k0 = 0; k0 < K; k0 += 64) {
#pragma unroll
    for (int c = 0; c < 4; ++c) async16(As + c * 2048 + lofs, ga + c * skip);
#pragma unroll
    for (int c = 0; c < 4; ++c) async16(Bs + c * 2048 + lofs, gb + c * skip);
    ga += 64;
    gb += 64;
    __syncthreads();
#pragma unroll
    for (int j = 0; j < 2; ++j) {
      bf16x8 afr[4], bfr[4];
      int ca = ((j * 4 + ksel) ^ sw) * 8;
#pragma unroll
      for (int i = 0; i < 4; ++i) {
        afr[i] = *(const bf16x8*)(As + (ar + i * 16) * 64 + ca);
        bfr[i] = *(const bf16x8*)(Bs + (br + i * 16) * 64 + ca);
      }
#pragma unroll
      for (int mt = 0; mt < 4; ++mt)
#pragma unroll
        for (int nt = 0; nt < 4; ++nt)
          acc[mt][nt] =
              __builtin_amdgcn_mfma_f32_16x16x32_bf16(afr[mt], bfr[nt], acc[mt][nt], 0, 0, 0);
    }
    __syncthreads();
  }

  if (GELU) {
    // epilogue: gelu -> bf16 into LDS (128x128), then coalesced 16B/lane stores
#pragma unroll
    for (int nt = 0; nt < 4; ++nt) {
      int nl = wn * 64 + nt * 16 + (lane & 15);
      float bv = bias[tile_n + nl];
#pragma unroll
      for (int mt = 0; mt < 4; ++mt) {
        int ml = wm * 64 + mt * 16 + (lane >> 4) * 4;
#pragma unroll
        for (int r = 0; r < 4; ++r)
          sh[(ml + r) * 128 + nl] = f2bf(gelu_f(acc[mt][nt][r] + bv));
      }
    }
    __syncthreads();
#pragma unroll
    for (int it = 0; it < 8; ++it) {
      int idx = it * 256 + tid;
      int row = idx >> 4, ch = (idx & 15) * 8;
      *(uint4*)(hout + (size_t)(tile_m + row) * Nn + tile_n + ch) =
          *(const uint4*)(sh + row * 128 + ch);
    }
  } else {
#pragma unroll
    for (int nt = 0; nt < 4; ++nt) {
      int n = tile_n + wn * 64 + nt * 16 + (lane & 15);
      float bv = bias[n];
#pragma unroll
      for (int mt = 0; mt < 4; ++mt) {
        int mbase = tile_m + wm * 64 + mt * 16 + (lane >> 4) * 4;
#pragma unroll
        for (int r = 0; r < 4; ++r) {
          int m = mbase + r;
          float v = acc[mt][nt][r] + bv;
          int bb = m >> 14, ntok = m & (N_ - 1);
          out0[((size_t)bb * 2 * N_ + N_ + ntok) * D_ + n] = v;
        }
      }
    }
  }
}

// ---------------------------------------------------------------------------
extern "C" void kernel_launch(void* const* d_in, const int* in_sizes, int n_in,
                              void* d_out, int out_size, void* d_ws, size_t ws_size,
                              hipStream_t stream) {
  const float* x = (const float*)d_in[0];
  const float* loc = (const float*)d_in[1];
  const float* src = (const float*)d_in[2];
  const float* wd = (const float*)d_in[7];
  const float* bd = (const float*)d_in[8];
  const float* g1 = (const float*)d_in[9];
  const float* b1 = (const float*)d_in[10];
  const float* cw = (const float*)d_in[11];
  const float* cb = (const float*)d_in[12];
  const float* g2 = (const float*)d_in[13];
  const float* b2 = (const float*)d_in[14];
  const float* fc1w = (const float*)d_in[15];
  const float* fc1b = (const float*)d_in[16];
  const float* fc2w = (const float*)d_in[17];
  const float* fc2b = (const float*)d_in[18];

  float* out0 = (float*)d_out;
  float* out1 = out0 + (size_t)B_ * 2 * N_ * D_;

  char* ws = (char*)d_ws;
  // Workspace layout (bytes). h (134 MB bf16) aliases featn(32MB)+fmap(32MB)+slack,
  // all dead by GEMM1 time.
  unsigned short* featn = (unsigned short*)(ws + 0);         //  33,554,432
  unsigned short* fmap = (unsigned short*)(ws + 33554432);   //  33,554,432
  unsigned short* h = (unsigned short*)(ws + 0);             // 134,217,728 (alias)
  unsigned short* ecat = (unsigned short*)(ws + 134217728);  //  41,943,040
  unsigned short* bt1 = (unsigned short*)(ws + 176160768);   //     655,360
  unsigned short* bt2 = (unsigned short*)(ws + 176816128);   //     524,288
  float* cntf = (float*)(ws + 177340416);                    //     262,144
  float* locex = (float*)(ws + 177602560);                   //     524,288
  int* head = (int*)(ws + 178126848);                        //     262,144
  int* nxt = (int*)(ws + 178388992);                         //     262,144

  hipMemsetAsync(head, 0xFF, (size_t)262144, stream);  // head[cell] = -1

  k_wconv<<<2304, 256, 0, stream>>>(fc1w, fc2w, bt1, bt2);
  k_delta<<<16384, 256, 0, stream>>>(x, loc, wd, bd, g1, b1, locex, out1, out0, head, nxt);
  k_gather<<<65536, 256, 0, stream>>>(x, head, nxt, featn, cntf);
  k_filter<<<65536, 256, 0, stream>>>(featn, cntf, fmap);
  k_patch<<<16384, 256, 0, stream>>>(src, locex, cw, cb, g2, b2, ecat);
  k_sample<<<16384, 256, 0, stream>>>(fmap, locex, ecat);
  k_gemm128<1><<<dim3(8, 512), 256, 0, stream>>>(ecat, bt1, fc1b, KIN_, HID_, h, nullptr);
  k_gemm128<0><<<dim3(2, 512), 256, 0, stream>>>(h, bt2, fc2b, HID_, D_, nullptr, out0);
}